// Round 5
// baseline (507.667 us; speedup 1.0000x reference)
//
#include <hip/hip_runtime.h>
#include <hip/hip_bf16.h>

typedef __hip_bfloat16 bf16;
typedef __attribute__((ext_vector_type(4))) float f32x4;
typedef __attribute__((ext_vector_type(8))) short s16x8;
typedef __attribute__((ext_vector_type(4))) short s16x4;

#define AS1 __attribute__((address_space(1)))
#define AS3 __attribute__((address_space(3)))

#define NB      4096        // batch rows
#define EPSV    1e-5f

// d_out element offsets: (r_out, m_out, mu, d) flattened (f32 elements)
#define OUT_R_OFF   0ull
#define OUT_M_OFF   8388608ull
#define OUT_MU_OFF  12582912ull
#define OUT_D_OFF   16777216ull

__device__ __forceinline__ short f2bf(float f) {
  union { bf16 b; short s; } u;
  u.b = __float2bfloat16(f);
  return u.s;
}
__device__ __forceinline__ float bf2f(short s) {
  union { float f; unsigned u; } v;
  v.u = ((unsigned)(unsigned short)s) << 16;
  return v.f;
}

// ---------------------------------------------------------------------------
// async 16B global->LDS (wave-uniform LDS base + lane*16)
// ---------------------------------------------------------------------------
__device__ __forceinline__ void gl_lds16(const bf16* g, void* l) {
  __builtin_amdgcn_global_load_lds((const AS1 unsigned int*)g,
                                   (AS3 unsigned int*)l, 16, 0, 0);
}

// Stage a 128-row x 64-col bf16 tile from a row-major matrix with ld=1024.
// LDS layout: row-major 128 B/row, per-row rotate swizzle of the eight 16B
// k-chunks: LDS chunk c of row r holds global chunk (c + r) & 7.
__device__ __forceinline__ void stage_tile_ld1024(const bf16* __restrict__ base,
                                                  int row0, int k0,
                                                  unsigned char* ldsTile,
                                                  int wave, int lane) {
  const int srow = lane >> 3;                 // row within 8-row chunk
  const int gch  = ((lane & 7) + srow) & 7;   // swizzled global k-chunk
  const bf16* g0 = base + ((size_t)(row0 + srow) << 10) + k0 + (gch << 3);
#pragma unroll
  for (int i = 0; i < 4; ++i) {
    const int q = wave * 4 + i;               // 1KB chunk id (8 rows each)
    gl_lds16(g0 + ((size_t)(q * 8) << 10), ldsTile + (q << 10));
  }
}

// read 8 bf16 (one MFMA operand frag) for tile-row r, global k-chunk g (0..7)
__device__ __forceinline__ s16x8 read_frag(const unsigned char* ldsTile, int r, int g) {
  return *(const s16x8*)(ldsTile + r * 128 + (((g - r) & 7) << 4));
}

struct __align__(16) TileLds {
  unsigned char A[16384];    // 128 x 64 bf16
  unsigned char Bm[16384];   // 128 x 64 bf16 (B^T rows = output cols)
  float colScale[128];
  float colShift[128];
  float rowGate[128];
};

struct __align__(16) PairLds {
  unsigned char A[16384];    // 128 x 64 bf16 (x tile, shared by both experts)
  unsigned char B[2][16384]; // two expert B tiles
};

// one BK=64 step: 16 ds_read_b128 + 32 MFMA per wave
__device__ __forceinline__ void mfma_step(const unsigned char* lA, const unsigned char* lB,
                                          int waveM, int waveN, int quad, int l15,
                                          f32x4 acc[4][4]) {
#pragma unroll
  for (int kk = 0; kk < 2; ++kk) {
    const int g = (kk << 2) + quad;
    s16x8 a[4], b[4];
#pragma unroll
    for (int i = 0; i < 4; ++i) a[i] = read_frag(lA, waveM * 64 + i * 16 + l15, g);
#pragma unroll
    for (int j = 0; j < 4; ++j) b[j] = read_frag(lB, waveN * 64 + j * 16 + l15, g);
#pragma unroll
    for (int i = 0; i < 4; ++i)
#pragma unroll
      for (int j = 0; j < 4; ++j)
        acc[i][j] = __builtin_amdgcn_mfma_f32_16x16x32_bf16(a[i], b[j], acc[i][j], 0, 0, 0);
  }
}

// ---------------------------------------------------------------------------
// 64x64 transpose+convert tile helper (f32 src -> bf16 dst, dst[C][R])
// ---------------------------------------------------------------------------
__device__ __forceinline__ void tr_tile(const float* __restrict__ src,
                                        short* __restrict__ dst,
                                        int R, int C, int r0, int c0,
                                        short (*t)[68], int tid) {
  const int cc = (tid & 15) * 4;
  const int rr = tid >> 4;                    // 0..15
#pragma unroll
  for (int s = 0; s < 4; ++s) {
    const int lr = s * 16 + rr;
    const float4 v = *(const float4*)(src + (size_t)(r0 + lr) * C + c0 + cc);
    s16x4 o;
    o[0] = f2bf(v.x); o[1] = f2bf(v.y); o[2] = f2bf(v.z); o[3] = f2bf(v.w);
    *(s16x4*)(&t[lr][cc]) = o;
  }
  __syncthreads();
#pragma unroll
  for (int s = 0; s < 4; ++s) {
    const int wl = s * 16 + rr;               // local dst row (= src col)
    s16x4 o;
#pragma unroll
    for (int u = 0; u < 4; ++u) o[u] = t[cc + u][wl];
    *(s16x4*)(dst + (size_t)(c0 + wl) * R + r0 + cc) = o;
  }
}

// ---------------------------------------------------------------------------
// prep_tr: all pre-moe transposes in ONE dispatch. grid 4448 flat.
// ---------------------------------------------------------------------------
__global__ __launch_bounds__(256) void prep_tr(
    const float* __restrict__ Wm_mu, const float* __restrict__ Wm_d,
    const float* __restrict__ Wp, const float* __restrict__ gw1_mu,
    const float* __restrict__ gw1_d, const float* __restrict__ se_w1,
    bf16* __restrict__ WmT_mu, bf16* __restrict__ WmT_d,
    bf16* __restrict__ WpT, bf16* __restrict__ Bg, bf16* __restrict__ sw1T) {
  __shared__ short t[64][68];
  const int b = blockIdx.x, tid = threadIdx.x;
  if (b < 2048) {
    const int batch = b >> 8, rem = b & 255;
    const size_t ofs = (size_t)batch << 20;
    tr_tile(Wm_mu + ofs, (short*)WmT_mu + ofs, 1024, 1024,
            (rem >> 4) * 64, (rem & 15) * 64, t, tid);
  } else if (b < 4096) {
    const int bb = b - 2048;
    const int batch = bb >> 8, rem = bb & 255;
    const size_t ofs = (size_t)batch << 20;
    tr_tile(Wm_d + ofs, (short*)WmT_d + ofs, 1024, 1024,
            (rem >> 4) * 64, (rem & 15) * 64, t, tid);
  } else if (b < 4352) {
    const int bb = b - 4096;
    tr_tile(Wp, (short*)WpT, 1024, 1024, (bb >> 4) * 64, (bb & 15) * 64, t, tid);
  } else if (b < 4368) {
    tr_tile(gw1_mu, (short*)Bg, 1024, 64, (b - 4352) * 64, 0, t, tid);
  } else if (b < 4384) {
    tr_tile(gw1_d, (short*)Bg + 65536, 1024, 64, (b - 4368) * 64, 0, t, tid);
  } else {
    const int i = (b - 4384) * 256 + tid;     // 0..16383
    const int u = i >> 10, d = i & 1023;
    ((short*)sw1T)[i] = f2bf(se_w1[d * 16 + u]);
  }
}

// ---------------------------------------------------------------------------
// prep_cvt: all f32->bf16 converts in ONE dispatch (4 f32/thread). grid 5127.
// ---------------------------------------------------------------------------
__global__ __launch_bounds__(256) void prep_cvt(const float* __restrict__ x,
                                                const float* __restrict__ Wv,
                                                const float* __restrict__ se_w2,
                                                bf16* __restrict__ xb,
                                                bf16* __restrict__ Wv_b,
                                                bf16* __restrict__ sw2b) {
  const int i = blockIdx.x * 256 + threadIdx.x;
  const float* src; bf16* dst; int idx;
  if (i < 1048576)      { src = x;     dst = xb;   idx = i; }
  else if (i < 1310720) { src = Wv;    dst = Wv_b; idx = i - 1048576; }
  else if (i < 1311744) { src = se_w2; dst = sw2b; idx = i - 1310720; }
  else return;
  const float4 v = ((const float4*)src)[idx];
  s16x4 o;
  o[0] = f2bf(v.x); o[1] = f2bf(v.y); o[2] = f2bf(v.z); o[3] = f2bf(v.w);
  *(s16x4*)((short*)dst + (size_t)idx * 4) = o;
}

// ---------------------------------------------------------------------------
// prep_tr2: decoder weight transposes (after moe frees WmT regions). grid 768.
// ---------------------------------------------------------------------------
__global__ __launch_bounds__(256) void prep_tr2(const float* __restrict__ Wr_dec,
                                                const float* __restrict__ Wm_dec,
                                                bf16* __restrict__ WrT,
                                                bf16* __restrict__ WmdT) {
  __shared__ short t[64][68];
  const int b = blockIdx.x, tid = threadIdx.x;
  if (b < 512) {
    tr_tile(Wr_dec, (short*)WrT, 1024, 2048, (b >> 5) * 64, (b & 31) * 64, t, tid);
  } else {
    const int bb = b - 512;
    tr_tile(Wm_dec, (short*)WmdT, 1024, 1024, (bb >> 4) * 64, (bb & 15) * 64, t, tid);
  }
}

// ---------------------------------------------------------------------------
// plain GEMM C[M][N] = A(ld1024,bf16) * Bt(ld1024,bf16)^T, bf16 out.
// used for WvpT = WpT * Wv^T  (i.e. (Wv*Wp)^T)
// ---------------------------------------------------------------------------
__global__ __launch_bounds__(256, 2) void gemm_bt(const bf16* __restrict__ A,
                                                  const bf16* __restrict__ Bt,
                                                  bf16* __restrict__ C, int N) {
  __shared__ TileLds lds;
  const int tid = threadIdx.x, lane = tid & 63, wave = tid >> 6;
  const int waveM = wave >> 1, waveN = wave & 1;
  const int quad = lane >> 4, l15 = lane & 15;
  const int m0 = blockIdx.x * 128, n0 = blockIdx.y * 128;
  f32x4 acc[4][4] = {};
  for (int kt = 0; kt < 16; ++kt) {
    __syncthreads();
    stage_tile_ld1024(A, m0, kt << 6, lds.A, wave, lane);
    stage_tile_ld1024(Bt, n0, kt << 6, lds.Bm, wave, lane);
    __builtin_amdgcn_s_waitcnt(0);
    __syncthreads();
    mfma_step(lds.A, lds.Bm, waveM, waveN, quad, l15, acc);
  }
#pragma unroll
  for (int i = 0; i < 4; ++i)
#pragma unroll
    for (int p = 0; p < 4; ++p) {
      const int r = m0 + waveM * 64 + i * 16 + (quad << 2) + p;
#pragma unroll
      for (int j = 0; j < 4; ++j) {
        const int c = n0 + waveN * 64 + j * 16 + l15;
        ((short*)C)[(size_t)r * N + c] = f2bf(acc[i][j][p]);
      }
    }
}

// ---------------------------------------------------------------------------
// hgates: H = relu(X @ Bg^T + b1cat) in LDS, then per-row 64->8 matvec +
// softmax -> gates. grid (32).
// ---------------------------------------------------------------------------
__global__ __launch_bounds__(256) void hgates(const bf16* __restrict__ xb,
                                              const bf16* __restrict__ Bg,
                                              const float* __restrict__ gb1_mu,
                                              const float* __restrict__ gb1_d,
                                              const float* __restrict__ gw2_mu,
                                              const float* __restrict__ gb2_mu,
                                              const float* __restrict__ gw2_d,
                                              const float* __restrict__ gb2_d,
                                              float* __restrict__ gates_mu,
                                              float* __restrict__ gates_d) {
  __shared__ TileLds lds;
  __shared__ float H[128][132];
  __shared__ float w2l[1024];
  __shared__ float b2l[16];
  const int tid = threadIdx.x, lane = tid & 63, wave = tid >> 6;
  const int waveM = wave >> 1, waveN = wave & 1;
  const int quad = lane >> 4, l15 = lane & 15;
  const int m0 = blockIdx.x * 128;
#pragma unroll
  for (int i = 0; i < 4; ++i) {
    const int idx = tid + i * 256;
    w2l[idx] = (idx < 512) ? gw2_mu[idx] : gw2_d[idx - 512];
  }
  if (tid < 16) b2l[tid] = (tid < 8) ? gb2_mu[tid] : gb2_d[tid - 8];
  f32x4 acc[4][4] = {};
  for (int kt = 0; kt < 16; ++kt) {
    __syncthreads();
    stage_tile_ld1024(xb, m0, kt << 6, lds.A, wave, lane);
    stage_tile_ld1024(Bg, 0, kt << 6, lds.Bm, wave, lane);
    __builtin_amdgcn_s_waitcnt(0);
    __syncthreads();
    mfma_step(lds.A, lds.Bm, waveM, waveN, quad, l15, acc);
  }
  float bias[4];
#pragma unroll
  for (int j = 0; j < 4; ++j) {
    const int c = waveN * 64 + j * 16 + l15;
    bias[j] = (c < 64) ? gb1_mu[c] : gb1_d[c - 64];
  }
#pragma unroll
  for (int i = 0; i < 4; ++i)
#pragma unroll
    for (int p = 0; p < 4; ++p) {
      const int r = waveM * 64 + i * 16 + (quad << 2) + p;
#pragma unroll
      for (int j = 0; j < 4; ++j) {
        const int c = waveN * 64 + j * 16 + l15;
        H[r][c] = fmaxf(acc[i][j][p] + bias[j], 0.f);
      }
    }
  __syncthreads();
  const int row = tid >> 1, path = tid & 1;
  float lg[8];
#pragma unroll
  for (int e = 0; e < 8; ++e) lg[e] = b2l[path * 8 + e];
  const float* wp = &w2l[path * 512];
  for (int j = 0; j < 64; ++j) {
    const float hv = H[row][path * 64 + j];
#pragma unroll
    for (int e = 0; e < 8; ++e) lg[e] += hv * wp[j * 8 + e];
  }
  float mx = lg[0];
#pragma unroll
  for (int e = 1; e < 8; ++e) mx = fmaxf(mx, lg[e]);
  float s = 0.f;
#pragma unroll
  for (int e = 0; e < 8; ++e) { lg[e] = __expf(lg[e] - mx); s += lg[e]; }
  const float inv = 1.f / s;
  float* gout = path ? gates_d : gates_mu;
#pragma unroll
  for (int e = 0; e < 8; ++e) gout[((size_t)(m0 + row) << 3) + e] = lg[e] * inv;
}

// ---------------------------------------------------------------------------
// fused MoE+attn, EXPERT-PAIRED: grid (32, 8, 2).
// Each pair-group stages the shared x-tile ONCE for two experts' B-tiles
// (A traffic -44%, barriers -44%); partial gated sums RMW into the output
// tile (block-exclusive, L2-resident) instead of a fin register array.
// ---------------------------------------------------------------------------
__global__ __launch_bounds__(256, 2) void moe_fused(
    const bf16* __restrict__ xb, const bf16* __restrict__ WmT_mu, const bf16* __restrict__ WmT_d,
    const bf16* __restrict__ WvpT,
    const float* __restrict__ bm_mu, const float* __restrict__ g_mu, const float* __restrict__ be_mu,
    const float* __restrict__ rm_mu, const float* __restrict__ rv_mu,
    const float* __restrict__ bm_d, const float* __restrict__ g_d, const float* __restrict__ be_d,
    const float* __restrict__ rm_d, const float* __restrict__ rv_d,
    const float* __restrict__ bp,
    const float* __restrict__ gates_mu, const float* __restrict__ gates_d,
    float* __restrict__ out_mu, float* __restrict__ out_d) {
  __shared__ PairLds lds;
  const int tid = threadIdx.x, lane = tid & 63, wave = tid >> 6;
  const int waveM = wave >> 1, waveN = wave & 1;
  const int quad = lane >> 4, l15 = lane & 15;
  const int m0 = blockIdx.x * 128, n0 = blockIdx.y * 128;
  const int path = blockIdx.z;
  const int nExp = (path == 0) ? 9 : 8;
  const bf16* Wall = (path == 0) ? WmT_mu : WmT_d;
  const float* gates = (path == 0) ? gates_mu : gates_d;
  const float* bmP = (path == 0) ? bm_mu : bm_d;
  const float* gP  = (path == 0) ? g_mu : g_d;
  const float* beP = (path == 0) ? be_mu : be_d;
  const float* rmP = (path == 0) ? rm_mu : rm_d;
  const float* rvP = (path == 0) ? rv_mu : rv_d;
  float* outp = (path == 0) ? out_mu : out_d;

  for (int e0 = 0; e0 < nExp; e0 += 2) {
    const int ne = (nExp - e0 >= 2) ? 2 : 1;
    const bool attn0 = (path == 0) && (e0 == 8);
    const bf16* B0 = attn0 ? WvpT : (Wall + ((size_t)e0 << 20));
    const bf16* B1 = Wall + ((size_t)(e0 + 1) << 20);   // used only if ne==2
    f32x4 acc[2][4][4] = {};
    for (int kt = 0; kt < 16; ++kt) {
      __syncthreads();   // protect LDS vs previous iter's frag reads
      stage_tile_ld1024(xb, m0, kt << 6, lds.A, wave, lane);
      stage_tile_ld1024(B0, n0, kt << 6, lds.B[0], wave, lane);
      if (ne == 2) stage_tile_ld1024(B1, n0, kt << 6, lds.B[1], wave, lane);
      __builtin_amdgcn_s_waitcnt(0);
      __syncthreads();
#pragma unroll
      for (int kk = 0; kk < 2; ++kk) {
        const int g = (kk << 2) + quad;
        s16x8 a[4], b0[4], b1[4];
#pragma unroll
        for (int i = 0; i < 4; ++i) a[i] = read_frag(lds.A, waveM * 64 + i * 16 + l15, g);
#pragma unroll
        for (int j = 0; j < 4; ++j) b0[j] = read_frag(lds.B[0], waveN * 64 + j * 16 + l15, g);
#pragma unroll
        for (int i = 0; i < 4; ++i)
#pragma unroll
          for (int j = 0; j < 4; ++j)
            acc[0][i][j] = __builtin_amdgcn_mfma_f32_16x16x32_bf16(a[i], b0[j], acc[0][i][j], 0, 0, 0);
        if (ne == 2) {
#pragma unroll
          for (int j = 0; j < 4; ++j) b1[j] = read_frag(lds.B[1], waveN * 64 + j * 16 + l15, g);
#pragma unroll
          for (int i = 0; i < 4; ++i)
#pragma unroll
            for (int j = 0; j < 4; ++j)
              acc[1][i][j] = __builtin_amdgcn_mfma_f32_16x16x32_bf16(a[i], b1[j], acc[1][i][j], 0, 0, 0);
        }
      }
    }
    // epilogue: params direct from global (L2-hot), partial sums RMW to out
    float sc[2][4], sh[2][4];
#pragma unroll
    for (int s = 0; s < 2; ++s) {
      if (s >= ne) break;
      const bool isA = (path == 0) && (e0 + s == 8);
#pragma unroll
      for (int j = 0; j < 4; ++j) {
        const int c = n0 + waveN * 64 + j * 16 + l15;
        if (isA) {
          sc[s][j] = 1.f; sh[s][j] = bp[c];
        } else {
          const int idx = ((e0 + s) << 10) + c;
          const float s_ = gP[idx] * rsqrtf(rvP[idx] + EPSV);
          sc[s][j] = s_;
          sh[s][j] = (bmP[idx] - rmP[idx]) * s_ + beP[idx];
        }
      }
    }
    const bool first = (e0 == 0);
#pragma unroll
    for (int i = 0; i < 4; ++i) {
      const int rb = m0 + waveM * 64 + i * 16 + (quad << 2);
      float gt0[4], gt1[4];
#pragma unroll
      for (int p = 0; p < 4; ++p) {
        gt0[p] = attn0 ? 1.f : gates[((size_t)(rb + p) << 3) + e0];
        gt1[p] = (ne == 2) ? gates[((size_t)(rb + p) << 3) + e0 + 1] : 0.f;
      }
#pragma unroll
      for (int j = 0; j < 4; ++j) {
        const int c = n0 + waveN * 64 + j * 16 + l15;
#pragma unroll
        for (int p = 0; p < 4; ++p) {
          float v0 = acc[0][i][j][p] * sc[0][j] + sh[0][j];
          if (!attn0) v0 = fmaxf(v0, 0.f);
          float t = gt0[p] * v0;
          if (ne == 2) {
            float v1 = fmaxf(acc[1][i][j][p] * sc[1][j] + sh[1][j], 0.f);
            t += gt1[p] * v1;
          }
          float* po = &outp[((size_t)(rb + p) << 10) + c];
          *po = (first ? 0.f : *po) + t;
        }
      }
    }
  }
}

// ---------------------------------------------------------------------------
// SE v3: latent = mu * sigmoid(relu(mu@se_w1)@se_w2). grid 512, 8 rows/block.
// ---------------------------------------------------------------------------
__global__ __launch_bounds__(256) void se3_kernel(const float* __restrict__ mu,
                                                  const bf16* __restrict__ sw1T,
                                                  const bf16* __restrict__ sw2b,
                                                  bf16* __restrict__ latent) {
  __shared__ float part[16][256];
  __shared__ float part2[16][17];
  __shared__ float s1[16];
  const int tid = threadIdx.x;
  for (int r = 0; r < 8; ++r) {
    const int row = blockIdx.x * 8 + r;
    const float4 m = *(const float4*)(mu + ((size_t)row << 10) + tid * 4);
#pragma unroll
    for (int u = 0; u < 16; ++u) {
      const s16x4 w = *(const s16x4*)((const short*)sw1T + u * 1024 + tid * 4);
      part[u][tid] = m.x * bf2f(w[0]) + m.y * bf2f(w[1])
                   + m.z * bf2f(w[2]) + m.w * bf2f(w[3]);
    }
    __syncthreads();
    {
      const int u = tid >> 4, c = tid & 15;
      float s = 0.f;
#pragma unroll
      for (int k = 0; k < 16; ++k) s += part[u][c * 16 + k];
      part2[u][c] = s;
    }
    __syncthreads();
    if (tid < 16) {
      float s = 0.f;
#pragma unroll
      for (int k = 0; k < 16; ++k) s += part2[tid][k];
      s1[tid] = fmaxf(s, 0.f);
    }
    __syncthreads();
    float o[4] = {0.f, 0.f, 0.f, 0.f};
#pragma unroll
    for (int u = 0; u < 16; ++u) {
      const s16x4 w = *(const s16x4*)((const short*)sw2b + u * 1024 + tid * 4);
      const float sv = s1[u];
      o[0] += sv * bf2f(w[0]); o[1] += sv * bf2f(w[1]);
      o[2] += sv * bf2f(w[2]); o[3] += sv * bf2f(w[3]);
    }
    const float mv[4] = {m.x, m.y, m.z, m.w};
    s16x4 ov;
#pragma unroll
    for (int t = 0; t < 4; ++t)
      ov[t] = f2bf(mv[t] / (1.f + __expf(-o[t])));
    *(s16x4*)((short*)latent + ((size_t)row << 10) + tid * 4) = ov;
    __syncthreads();
  }
}

// ---------------------------------------------------------------------------
// decoders: r_out = sigmoid(bn(latent@Wr+br)) [N=2048], m_out [N=1024].
// grid (32, 24): nt<16 -> r path, else m path.
// ---------------------------------------------------------------------------
__global__ __launch_bounds__(256, 2) void dec_kernel(
    const bf16* __restrict__ latent, const bf16* __restrict__ WrT, const bf16* __restrict__ WmdT,
    const float* __restrict__ br, const float* __restrict__ gr, const float* __restrict__ betar,
    const float* __restrict__ rmr, const float* __restrict__ rvr,
    const float* __restrict__ bm, const float* __restrict__ gm, const float* __restrict__ betam,
    const float* __restrict__ rmm, const float* __restrict__ rvm,
    float* __restrict__ out) {
  __shared__ TileLds lds;
  const int tid = threadIdx.x, lane = tid & 63, wave = tid >> 6;
  const int waveM = wave >> 1, waveN = wave & 1;
  const int quad = lane >> 4, l15 = lane & 15;
  const int m0 = blockIdx.x * 128;
  const int nt = blockIdx.y;
  const bool isR = nt < 16;
  const int n0 = (isR ? nt : nt - 16) * 128;
  const bf16* Bt = isR ? WrT : WmdT;
  f32x4 acc[4][4] = {};
  for (int kt = 0; kt < 16; ++kt) {
    __syncthreads();
    stage_tile_ld1024(latent, m0, kt << 6, lds.A, wave, lane);
    stage_tile_ld1024(Bt, n0, kt << 6, lds.Bm, wave, lane);
    if (kt == 0 && tid < 128) {
      const int c = n0 + tid;
      const float bb = isR ? br[c] : bm[c];
      const float gg = isR ? gr[c] : gm[c];
      const float be = isR ? betar[c] : betam[c];
      const float rm = isR ? rmr[c] : rmm[c];
      const float rv = isR ? rvr[c] : rvm[c];
      const float sc = gg * rsqrtf(rv + EPSV);
      lds.colScale[tid] = sc;
      lds.colShift[tid] = (bb - rm) * sc + be;
    }
    __builtin_amdgcn_s_waitcnt(0);
    __syncthreads();
    mfma_step(lds.A, lds.Bm, waveM, waveN, quad, l15, acc);
  }
#pragma unroll
  for (int i = 0; i < 4; ++i)
#pragma unroll
    for (int p = 0; p < 4; ++p) {
      const int r = m0 + waveM * 64 + i * 16 + (quad << 2) + p;
#pragma unroll
      for (int j = 0; j < 4; ++j) {
        const int cl = waveN * 64 + j * 16 + l15;
        float v = acc[i][j][p] * lds.colScale[cl] + lds.colShift[cl];
        v = 1.f / (1.f + __expf(-v));
        const size_t idx = isR ? ((size_t)r * 2048 + n0 + cl)
                               : (OUT_M_OFF + (size_t)r * 1024 + n0 + cl);
        out[idx] = v;
      }
    }
}

// ---------------------------------------------------------------------------
extern "C" void kernel_launch(void* const* d_in, const int* in_sizes, int n_in,
                              void* d_out, int out_size, void* d_ws, size_t ws_size,
                              hipStream_t stream) {
  (void)in_sizes; (void)n_in; (void)out_size; (void)ws_size;
  const float* x      = (const float*)d_in[0];
  const float* Wm_mu  = (const float*)d_in[1];
  const float* bm_mu  = (const float*)d_in[2];
  const float* g_mu   = (const float*)d_in[3];
  const float* be_mu  = (const float*)d_in[4];
  const float* rm_mu  = (const float*)d_in[5];
  const float* rv_mu  = (const float*)d_in[6];
  const float* Wm_d   = (const float*)d_in[7];
  const float* bm_d   = (const float*)d_in[8];
  const float* g_d    = (const float*)d_in[9];
  const float* be_d   = (const float*)d_in[10];
  const float* rm_d   = (const float*)d_in[11];
  const float* rv_d   = (const float*)d_in[12];
  const float* gw1_mu = (const float*)d_in[13];
  const float* gb1_mu = (const float*)d_in[14];
  const float* gw2_mu = (const float*)d_in[15];
  const float* gb2_mu = (const float*)d_in[16];
  const float* gw1_d  = (const float*)d_in[17];
  const float* gb1_d  = (const float*)d_in[18];
  const float* gw2_d  = (const float*)d_in[19];
  const float* gb2_d  = (const float*)d_in[20];
  // d_in[21]=Wq, d_in[22]=Wk: dead (softmax over a 1x1 score == 1)
  const float* Wv     = (const float*)d_in[23];
  const float* Wp     = (const float*)d_in[24];
  const float* bp     = (const float*)d_in[25];
  const float* se_w1  = (const float*)d_in[26];
  const float* se_w2  = (const float*)d_in[27];
  const float* Wr_dec = (const float*)d_in[28];
  const float* br_dec = (const float*)d_in[29];
  const float* gr     = (const float*)d_in[30];
  const float* betar  = (const float*)d_in[31];
  const float* rmr    = (const float*)d_in[32];
  const float* rvr    = (const float*)d_in[33];
  const float* Wm_dec = (const float*)d_in[34];
  const float* bm_dec = (const float*)d_in[35];
  const float* gm     = (const float*)d_in[36];
  const float* betam  = (const float*)d_in[37];
  const float* rmm    = (const float*)d_in[38];
  const float* rvm    = (const float*)d_in[39];

  unsigned char* ws = (unsigned char*)d_ws;
  bf16* xb      = (bf16*)(ws + 0);           //  8 MiB (dead after moe_fused)
  bf16* WmT_mu  = (bf16*)(ws + 8388608);     // 16 MiB (dead after moe_fused)
  bf16* WmT_d   = (bf16*)(ws + 25165824);    // 16 MiB (dead after moe_fused)
  bf16* WvpT    = (bf16*)(ws + 41943040);    //  2 MiB
  float* gates_mu = (float*)(ws + 44040192); // 128 KiB
  float* gates_d  = (float*)(ws + 44171264); // 128 KiB
  bf16* latent  = (bf16*)(ws + 0);           //  8 MiB (overlays xb, post-moe)
  bf16* WrT     = (bf16*)(ws + 8388608);     //  4 MiB (overlays WmT_mu, post-moe)
  bf16* WmdT    = (bf16*)(ws + 12582912);    //  2 MiB

  float* out = (float*)d_out;
  float* out_mu = out + OUT_MU_OFF;
  float* out_d  = out + OUT_D_OFF;
  // Scratch in d_out regions not yet written at use time:
  bf16* Bg    = (bf16*)(out + 524288);       // [128][1024] bf16 (256 KiB, r_out region)
  bf16* sw1T  = (bf16*)(out + 589824);       // [16][1024] bf16 (32 KiB)
  bf16* sw2b  = (bf16*)(out + 598016);       // [16][1024] bf16 (32 KiB)
  bf16* WpT   = (bf16*)(out + OUT_MU_OFF);            // 2 MiB (mu region, pre-moe)
  bf16* Wv_b  = (bf16*)(out + OUT_MU_OFF + 524288);   // 2 MiB

  const dim3 blk(256, 1, 1);

  // 1. all pre-moe transposes (one dispatch)
  prep_tr<<<dim3(4448, 1, 1), blk, 0, stream>>>(
      Wm_mu, Wm_d, Wp, gw1_mu, gw1_d, se_w1,
      WmT_mu, WmT_d, WpT, Bg, sw1T);
  // 2. all converts (one dispatch)
  prep_cvt<<<dim3(5127, 1, 1), blk, 0, stream>>>(x, Wv, se_w2, xb, Wv_b, sw2b);
  // 3. WvpT = WpT * Wv_b^T = (Wv*Wp)^T
  gemm_bt<<<dim3(8, 8, 1), blk, 0, stream>>>(WpT, Wv_b, WvpT, 1024);
  // 4. gate network (H-GEMM + softmax fused)
  hgates<<<dim3(32, 1, 1), blk, 0, stream>>>(xb, Bg, gb1_mu, gb1_d,
                                             gw2_mu, gb2_mu, gw2_d, gb2_d,
                                             gates_mu, gates_d);
  // 5. fused MoE, expert-paired (+ attn folded into mu path as 9th expert)
  moe_fused<<<dim3(32, 8, 2), blk, 0, stream>>>(
      xb, WmT_mu, WmT_d, WvpT, bm_mu, g_mu, be_mu, rm_mu, rv_mu,
      bm_d, g_d, be_d, rm_d, rv_d, bp, gates_mu, gates_d, out_mu, out_d);
  // 6. decoder weight transposes (overlay WmT regions, now dead)
  prep_tr2<<<dim3(768, 1, 1), blk, 0, stream>>>(Wr_dec, Wm_dec, WrT, WmdT);
  // 7. SE -> latent
  se3_kernel<<<dim3(512, 1, 1), blk, 0, stream>>>(out_mu, sw1T, sw2b, latent);
  // 8. decoders with fused BN+sigmoid epilogue
  dec_kernel<<<dim3(32, 24, 1), blk, 0, stream>>>(
      latent, WrT, WmdT, br_dec, gr, betar, rmr, rvr,
      bm_dec, gm, betam, rmm, rvm, out);
}

// Round 6
// 465.205 us; speedup vs baseline: 1.0913x; 1.0913x over previous
//
#include <hip/hip_runtime.h>
#include <hip/hip_bf16.h>

typedef __hip_bfloat16 bf16;
typedef __attribute__((ext_vector_type(4))) float f32x4;
typedef __attribute__((ext_vector_type(8))) short s16x8;
typedef __attribute__((ext_vector_type(4))) short s16x4;

#define AS1 __attribute__((address_space(1)))
#define AS3 __attribute__((address_space(3)))

#define NB      4096        // batch rows
#define EPSV    1e-5f

// d_out element offsets: (r_out, m_out, mu, d) flattened (f32 elements)
#define OUT_R_OFF   0ull
#define OUT_M_OFF   8388608ull
#define OUT_MU_OFF  12582912ull
#define OUT_D_OFF   16777216ull

__device__ __forceinline__ short f2bf(float f) {
  union { bf16 b; short s; } u;
  u.b = __float2bfloat16(f);
  return u.s;
}
__device__ __forceinline__ float bf2f(short s) {
  union { float f; unsigned u; } v;
  v.u = ((unsigned)(unsigned short)s) << 16;
  return v.f;
}

// ---------------------------------------------------------------------------
// async 16B global->LDS (wave-uniform LDS base + lane*16)
// ---------------------------------------------------------------------------
__device__ __forceinline__ void gl_lds16(const bf16* g, void* l) {
  __builtin_amdgcn_global_load_lds((const AS1 unsigned int*)g,
                                   (AS3 unsigned int*)l, 16, 0, 0);
}

// Stage a 128-row x 64-col bf16 tile from a row-major matrix with ld=1024.
// LDS layout: row-major 128 B/row, per-row rotate swizzle of the eight 16B
// k-chunks: LDS chunk c of row r holds global chunk (c + r) & 7.
__device__ __forceinline__ void stage_tile_ld1024(const bf16* __restrict__ base,
                                                  int row0, int k0,
                                                  unsigned char* ldsTile,
                                                  int wave, int lane) {
  const int srow = lane >> 3;                 // row within 8-row chunk
  const int gch  = ((lane & 7) + srow) & 7;   // swizzled global k-chunk
  const bf16* g0 = base + ((size_t)(row0 + srow) << 10) + k0 + (gch << 3);
#pragma unroll
  for (int i = 0; i < 4; ++i) {
    const int q = wave * 4 + i;               // 1KB chunk id (8 rows each)
    gl_lds16(g0 + ((size_t)(q * 8) << 10), ldsTile + (q << 10));
  }
}

// read 8 bf16 (one MFMA operand frag) for tile-row r, global k-chunk g (0..7)
__device__ __forceinline__ s16x8 read_frag(const unsigned char* ldsTile, int r, int g) {
  return *(const s16x8*)(ldsTile + r * 128 + (((g - r) & 7) << 4));
}

struct __align__(16) TileAB {
  unsigned char A[16384];    // 128 x 64 bf16
  unsigned char Bm[16384];   // 128 x 64 bf16 (B^T rows = output cols)
};

struct __align__(16) TileLds {    // TileAB + epilogue params (dec kernel)
  unsigned char A[16384];
  unsigned char Bm[16384];
  float colScale[128];
  float colShift[128];
};

// one BK=64 step: 16 ds_read_b128 + 32 MFMA per wave
__device__ __forceinline__ void mfma_step(const unsigned char* lA, const unsigned char* lB,
                                          int waveM, int waveN, int quad, int l15,
                                          f32x4 acc[4][4]) {
#pragma unroll
  for (int kk = 0; kk < 2; ++kk) {
    const int g = (kk << 2) + quad;
    s16x8 a[4], b[4];
#pragma unroll
    for (int i = 0; i < 4; ++i) a[i] = read_frag(lA, waveM * 64 + i * 16 + l15, g);
#pragma unroll
    for (int j = 0; j < 4; ++j) b[j] = read_frag(lB, waveN * 64 + j * 16 + l15, g);
#pragma unroll
    for (int i = 0; i < 4; ++i)
#pragma unroll
      for (int j = 0; j < 4; ++j)
        acc[i][j] = __builtin_amdgcn_mfma_f32_16x16x32_bf16(a[i], b[j], acc[i][j], 0, 0, 0);
  }
}

// ---------------------------------------------------------------------------
// 64x64 transpose+convert tile helper (f32 src -> bf16 dst, dst[C][R])
// ---------------------------------------------------------------------------
__device__ __forceinline__ void tr_tile(const float* __restrict__ src,
                                        short* __restrict__ dst,
                                        int R, int C, int r0, int c0,
                                        short (*t)[68], int tid) {
  const int cc = (tid & 15) * 4;
  const int rr = tid >> 4;                    // 0..15
#pragma unroll
  for (int s = 0; s < 4; ++s) {
    const int lr = s * 16 + rr;
    const float4 v = *(const float4*)(src + (size_t)(r0 + lr) * C + c0 + cc);
    s16x4 o;
    o[0] = f2bf(v.x); o[1] = f2bf(v.y); o[2] = f2bf(v.z); o[3] = f2bf(v.w);
    *(s16x4*)(&t[lr][cc]) = o;
  }
  __syncthreads();
#pragma unroll
  for (int s = 0; s < 4; ++s) {
    const int wl = s * 16 + rr;               // local dst row (= src col)
    s16x4 o;
#pragma unroll
    for (int u = 0; u < 4; ++u) o[u] = t[cc + u][wl];
    *(s16x4*)(dst + (size_t)(c0 + wl) * R + r0 + cc) = o;
  }
}

// ---------------------------------------------------------------------------
// prep_all: ALL pre-moe transposes + converts in ONE dispatch. grid 9575:
// [0,2048)    Wm_mu -> WmT_mu          [2048,4096) Wm_d -> WmT_d
// [4096,4352) Wp -> WpT                [4352,4368) gw1_mu -> Bg[0:64]
// [4368,4384) gw1_d -> Bg[64:128]      [4384,4448) se_w1 -> sw1T (gather)
// [4448,9575) converts: x->xb, Wv->Wv_b, se_w2->sw2b (4 f32/thread)
// ---------------------------------------------------------------------------
__global__ __launch_bounds__(256) void prep_all(
    const float* __restrict__ Wm_mu, const float* __restrict__ Wm_d,
    const float* __restrict__ Wp, const float* __restrict__ gw1_mu,
    const float* __restrict__ gw1_d, const float* __restrict__ se_w1,
    const float* __restrict__ x, const float* __restrict__ Wv,
    const float* __restrict__ se_w2,
    bf16* __restrict__ WmT_mu, bf16* __restrict__ WmT_d,
    bf16* __restrict__ WpT, bf16* __restrict__ Bg, bf16* __restrict__ sw1T,
    bf16* __restrict__ xb, bf16* __restrict__ Wv_b, bf16* __restrict__ sw2b) {
  __shared__ short t[64][68];
  const int b = blockIdx.x, tid = threadIdx.x;
  if (b < 2048) {
    const int batch = b >> 8, rem = b & 255;
    const size_t ofs = (size_t)batch << 20;
    tr_tile(Wm_mu + ofs, (short*)WmT_mu + ofs, 1024, 1024,
            (rem >> 4) * 64, (rem & 15) * 64, t, tid);
  } else if (b < 4096) {
    const int bb = b - 2048;
    const int batch = bb >> 8, rem = bb & 255;
    const size_t ofs = (size_t)batch << 20;
    tr_tile(Wm_d + ofs, (short*)WmT_d + ofs, 1024, 1024,
            (rem >> 4) * 64, (rem & 15) * 64, t, tid);
  } else if (b < 4352) {
    const int bb = b - 4096;
    tr_tile(Wp, (short*)WpT, 1024, 1024, (bb >> 4) * 64, (bb & 15) * 64, t, tid);
  } else if (b < 4368) {
    tr_tile(gw1_mu, (short*)Bg, 1024, 64, (b - 4352) * 64, 0, t, tid);
  } else if (b < 4384) {
    tr_tile(gw1_d, (short*)Bg + 65536, 1024, 64, (b - 4368) * 64, 0, t, tid);
  } else if (b < 4448) {
    const int i = (b - 4384) * 256 + tid;     // 0..16383
    const int u = i >> 10, d = i & 1023;
    ((short*)sw1T)[i] = f2bf(se_w1[d * 16 + u]);
  } else {
    const int i = (b - 4448) * 256 + tid;
    const float* src; bf16* dst; int idx;
    if (i < 1048576)      { src = x;     dst = xb;   idx = i; }
    else if (i < 1310720) { src = Wv;    dst = Wv_b; idx = i - 1048576; }
    else if (i < 1311744) { src = se_w2; dst = sw2b; idx = i - 1310720; }
    else return;
    const float4 v = ((const float4*)src)[idx];
    s16x4 o;
    o[0] = f2bf(v.x); o[1] = f2bf(v.y); o[2] = f2bf(v.z); o[3] = f2bf(v.w);
    *(s16x4*)((short*)dst + (size_t)idx * 4) = o;
  }
}

// ---------------------------------------------------------------------------
// gemm_gate: one dispatch, grid 96.
// b<64:  WvpT[128x128 tile] = WpT * Wv_b^T  (m0=(b&7)*128, n0=(b>>3)*128)
// b>=64: hgates block (m0=(b-64)*128): H=relu(X@Bg^T+b1) in LDS -> softmax
// ---------------------------------------------------------------------------
__global__ __launch_bounds__(256) void gemm_gate(
    const bf16* __restrict__ WpT, const bf16* __restrict__ Wv_b,
    bf16* __restrict__ WvpT,
    const bf16* __restrict__ xb, const bf16* __restrict__ Bg,
    const float* __restrict__ gb1_mu, const float* __restrict__ gb1_d,
    const float* __restrict__ gw2_mu, const float* __restrict__ gb2_mu,
    const float* __restrict__ gw2_d, const float* __restrict__ gb2_d,
    float* __restrict__ gates_mu, float* __restrict__ gates_d) {
  __shared__ TileAB lds;
  __shared__ float H[128][132];
  __shared__ float w2l[1024];
  __shared__ float b2l[16];
  const int tid = threadIdx.x, lane = tid & 63, wave = tid >> 6;
  const int waveM = wave >> 1, waveN = wave & 1;
  const int quad = lane >> 4, l15 = lane & 15;
  if (blockIdx.x < 64) {
    // ---- WvpT tile ----
    const int m0 = (blockIdx.x & 7) * 128, n0 = (blockIdx.x >> 3) * 128;
    f32x4 acc[4][4] = {};
    for (int kt = 0; kt < 16; ++kt) {
      __syncthreads();
      stage_tile_ld1024(WpT, m0, kt << 6, lds.A, wave, lane);
      stage_tile_ld1024(Wv_b, n0, kt << 6, lds.Bm, wave, lane);
      __builtin_amdgcn_s_waitcnt(0);
      __syncthreads();
      mfma_step(lds.A, lds.Bm, waveM, waveN, quad, l15, acc);
    }
#pragma unroll
    for (int i = 0; i < 4; ++i)
#pragma unroll
      for (int p = 0; p < 4; ++p) {
        const int r = m0 + waveM * 64 + i * 16 + (quad << 2) + p;
#pragma unroll
        for (int j = 0; j < 4; ++j) {
          const int c = n0 + waveN * 64 + j * 16 + l15;
          ((short*)WvpT)[(size_t)r * 1024 + c] = f2bf(acc[i][j][p]);
        }
      }
  } else {
    // ---- gate network ----
    const int m0 = (blockIdx.x - 64) * 128;
#pragma unroll
    for (int i = 0; i < 4; ++i) {
      const int idx = tid + i * 256;
      w2l[idx] = (idx < 512) ? gw2_mu[idx] : gw2_d[idx - 512];
    }
    if (tid < 16) b2l[tid] = (tid < 8) ? gb2_mu[tid] : gb2_d[tid - 8];
    f32x4 acc[4][4] = {};
    for (int kt = 0; kt < 16; ++kt) {
      __syncthreads();
      stage_tile_ld1024(xb, m0, kt << 6, lds.A, wave, lane);
      stage_tile_ld1024(Bg, 0, kt << 6, lds.Bm, wave, lane);
      __builtin_amdgcn_s_waitcnt(0);
      __syncthreads();
      mfma_step(lds.A, lds.Bm, waveM, waveN, quad, l15, acc);
    }
    float bias[4];
#pragma unroll
    for (int j = 0; j < 4; ++j) {
      const int c = waveN * 64 + j * 16 + l15;
      bias[j] = (c < 64) ? gb1_mu[c] : gb1_d[c - 64];
    }
#pragma unroll
    for (int i = 0; i < 4; ++i)
#pragma unroll
      for (int p = 0; p < 4; ++p) {
        const int r = waveM * 64 + i * 16 + (quad << 2) + p;
#pragma unroll
        for (int j = 0; j < 4; ++j) {
          const int c = waveN * 64 + j * 16 + l15;
          H[r][c] = fmaxf(acc[i][j][p] + bias[j], 0.f);
        }
      }
    __syncthreads();
    const int row = tid >> 1, path = tid & 1;
    float lg[8];
#pragma unroll
    for (int e = 0; e < 8; ++e) lg[e] = b2l[path * 8 + e];
    const float* wp = &w2l[path * 512];
    for (int j = 0; j < 64; ++j) {
      const float hv = H[row][path * 64 + j];
#pragma unroll
      for (int e = 0; e < 8; ++e) lg[e] += hv * wp[j * 8 + e];
    }
    float mx = lg[0];
#pragma unroll
    for (int e = 1; e < 8; ++e) mx = fmaxf(mx, lg[e]);
    float s = 0.f;
#pragma unroll
    for (int e = 0; e < 8; ++e) { lg[e] = __expf(lg[e] - mx); s += lg[e]; }
    const float inv = 1.f / s;
    float* gout = path ? gates_d : gates_mu;
#pragma unroll
    for (int e = 0; e < 8; ++e) gout[((size_t)(m0 + row) << 3) + e] = lg[e] * inv;
  }
}

// ---------------------------------------------------------------------------
// fused MoE+attn (round-4 structure, the measured 163 us / MfmaUtil 39%
// plateau): grid (32, 8, 2). z=0: mu = sum_e gate*relu(bn(x@W_e)) + x@Wvp+bp.
// Epilogue params read from global (L2-hot) -- no branch in the K-loop.
// ---------------------------------------------------------------------------
__global__ __launch_bounds__(256, 2) void moe_fused(
    const bf16* __restrict__ xb, const bf16* __restrict__ WmT_mu, const bf16* __restrict__ WmT_d,
    const bf16* __restrict__ WvpT,
    const float* __restrict__ bm_mu, const float* __restrict__ g_mu, const float* __restrict__ be_mu,
    const float* __restrict__ rm_mu, const float* __restrict__ rv_mu,
    const float* __restrict__ bm_d, const float* __restrict__ g_d, const float* __restrict__ be_d,
    const float* __restrict__ rm_d, const float* __restrict__ rv_d,
    const float* __restrict__ bp,
    const float* __restrict__ gates_mu, const float* __restrict__ gates_d,
    float* __restrict__ out_mu, float* __restrict__ out_d) {
  __shared__ TileAB lds;
  const int tid = threadIdx.x, lane = tid & 63, wave = tid >> 6;
  const int waveM = wave >> 1, waveN = wave & 1;
  const int quad = lane >> 4, l15 = lane & 15;
  const int m0 = blockIdx.x * 128, n0 = blockIdx.y * 128;
  const int path = blockIdx.z;
  const int nExp = (path == 0) ? 9 : 8;
  const bf16* Wall = (path == 0) ? WmT_mu : WmT_d;
  const float* gates = (path == 0) ? gates_mu : gates_d;
  const float* bmP = (path == 0) ? bm_mu : bm_d;
  const float* gP  = (path == 0) ? g_mu : g_d;
  const float* beP = (path == 0) ? be_mu : be_d;
  const float* rmP = (path == 0) ? rm_mu : rm_d;
  const float* rvP = (path == 0) ? rv_mu : rv_d;

  f32x4 fin[4][4] = {};

  for (int e = 0; e < nExp; ++e) {
    const bool isAttn = (path == 0) && (e == 8);
    const bf16* Bmat = isAttn ? WvpT : (Wall + ((size_t)e << 20));
    f32x4 acc[4][4] = {};
    for (int kt = 0; kt < 16; ++kt) {
      __syncthreads();   // protect LDS vs previous iter's frag reads
      stage_tile_ld1024(xb, m0, kt << 6, lds.A, wave, lane);
      stage_tile_ld1024(Bmat, n0, kt << 6, lds.Bm, wave, lane);
      __builtin_amdgcn_s_waitcnt(0);
      __syncthreads();
      mfma_step(lds.A, lds.Bm, waveM, waveN, quad, l15, acc);
    }
    // epilogue: BN scale/shift + gate from global (L2-hot), fp32 regs
    float sc[4], sh[4];
#pragma unroll
    for (int j = 0; j < 4; ++j) {
      const int c = n0 + waveN * 64 + j * 16 + l15;
      if (isAttn) {
        sc[j] = 1.f; sh[j] = bp[c];
      } else {
        const int idx = (e << 10) + c;
        const float s_ = gP[idx] * rsqrtf(rvP[idx] + EPSV);
        sc[j] = s_;
        sh[j] = (bmP[idx] - rmP[idx]) * s_ + beP[idx];
      }
    }
#pragma unroll
    for (int i = 0; i < 4; ++i) {
      const int rb = m0 + waveM * 64 + i * 16 + (quad << 2);
      float gt[4];
#pragma unroll
      for (int p = 0; p < 4; ++p)
        gt[p] = isAttn ? 1.f : gates[((size_t)(rb + p) << 3) + e];
#pragma unroll
      for (int j = 0; j < 4; ++j)
#pragma unroll
        for (int p = 0; p < 4; ++p) {
          float v = acc[i][j][p] * sc[j] + sh[j];
          if (!isAttn) v = fmaxf(v, 0.f);
          fin[i][j][p] += gt[p] * v;
        }
    }
  }
  float* outp = (path == 0) ? out_mu : out_d;
#pragma unroll
  for (int i = 0; i < 4; ++i)
#pragma unroll
    for (int p = 0; p < 4; ++p) {
      const int r = m0 + waveM * 64 + i * 16 + (quad << 2) + p;
#pragma unroll
      for (int j = 0; j < 4; ++j) {
        const int c = n0 + waveN * 64 + j * 16 + l15;
        outp[((size_t)r << 10) + c] = fin[i][j][p];
      }
    }
}

// ---------------------------------------------------------------------------
// post_moe: one dispatch, grid 1280.
// b<512:  Wr_dec[1024][2048] -> WrT tile     b in [512,768): Wm_dec -> WmdT
// b>=768: SE block (8 rows): latent = mu * sigmoid(relu(mu@se_w1)@se_w2)
// ---------------------------------------------------------------------------
__global__ __launch_bounds__(256) void post_moe(
    const float* __restrict__ Wr_dec, const float* __restrict__ Wm_dec,
    bf16* __restrict__ WrT, bf16* __restrict__ WmdT,
    const float* __restrict__ mu, const bf16* __restrict__ sw1T,
    const bf16* __restrict__ sw2b, bf16* __restrict__ latent) {
  __shared__ short t[64][68];
  __shared__ float part[16][256];
  __shared__ float part2[16][17];
  __shared__ float s1[16];
  const int b = blockIdx.x, tid = threadIdx.x;
  if (b < 512) {
    tr_tile(Wr_dec, (short*)WrT, 1024, 2048, (b >> 5) * 64, (b & 31) * 64, t, tid);
  } else if (b < 768) {
    const int bb = b - 512;
    tr_tile(Wm_dec, (short*)WmdT, 1024, 1024, (bb >> 4) * 64, (bb & 15) * 64, t, tid);
  } else {
    const int blk = b - 768;
    for (int r = 0; r < 8; ++r) {
      const int row = blk * 8 + r;
      const float4 m = *(const float4*)(mu + ((size_t)row << 10) + tid * 4);
#pragma unroll
      for (int u = 0; u < 16; ++u) {
        const s16x4 w = *(const s16x4*)((const short*)sw1T + u * 1024 + tid * 4);
        part[u][tid] = m.x * bf2f(w[0]) + m.y * bf2f(w[1])
                     + m.z * bf2f(w[2]) + m.w * bf2f(w[3]);
      }
      __syncthreads();
      {
        const int u = tid >> 4, c = tid & 15;
        float s = 0.f;
#pragma unroll
        for (int k = 0; k < 16; ++k) s += part[u][c * 16 + k];
        part2[u][c] = s;
      }
      __syncthreads();
      if (tid < 16) {
        float s = 0.f;
#pragma unroll
        for (int k = 0; k < 16; ++k) s += part2[tid][k];
        s1[tid] = fmaxf(s, 0.f);
      }
      __syncthreads();
      float o[4] = {0.f, 0.f, 0.f, 0.f};
#pragma unroll
      for (int u = 0; u < 16; ++u) {
        const s16x4 w = *(const s16x4*)((const short*)sw2b + u * 1024 + tid * 4);
        const float sv = s1[u];
        o[0] += sv * bf2f(w[0]); o[1] += sv * bf2f(w[1]);
        o[2] += sv * bf2f(w[2]); o[3] += sv * bf2f(w[3]);
      }
      const float mv[4] = {m.x, m.y, m.z, m.w};
      s16x4 ov;
#pragma unroll
      for (int tt = 0; tt < 4; ++tt)
        ov[tt] = f2bf(mv[tt] / (1.f + __expf(-o[tt])));
      *(s16x4*)((short*)latent + ((size_t)row << 10) + tid * 4) = ov;
      __syncthreads();
    }
  }
}

// ---------------------------------------------------------------------------
// decoders: r_out = sigmoid(bn(latent@Wr+br)) [N=2048], m_out [N=1024].
// grid (32, 24): nt<16 -> r path, else m path.
// ---------------------------------------------------------------------------
__global__ __launch_bounds__(256, 2) void dec_kernel(
    const bf16* __restrict__ latent, const bf16* __restrict__ WrT, const bf16* __restrict__ WmdT,
    const float* __restrict__ br, const float* __restrict__ gr, const float* __restrict__ betar,
    const float* __restrict__ rmr, const float* __restrict__ rvr,
    const float* __restrict__ bm, const float* __restrict__ gm, const float* __restrict__ betam,
    const float* __restrict__ rmm, const float* __restrict__ rvm,
    float* __restrict__ out) {
  __shared__ TileLds lds;
  const int tid = threadIdx.x, lane = tid & 63, wave = tid >> 6;
  const int waveM = wave >> 1, waveN = wave & 1;
  const int quad = lane >> 4, l15 = lane & 15;
  const int m0 = blockIdx.x * 128;
  const int nt = blockIdx.y;
  const bool isR = nt < 16;
  const int n0 = (isR ? nt : nt - 16) * 128;
  const bf16* Bt = isR ? WrT : WmdT;
  f32x4 acc[4][4] = {};
  for (int kt = 0; kt < 16; ++kt) {
    __syncthreads();
    stage_tile_ld1024(latent, m0, kt << 6, lds.A, wave, lane);
    stage_tile_ld1024(Bt, n0, kt << 6, lds.Bm, wave, lane);
    if (kt == 0 && tid < 128) {
      const int c = n0 + tid;
      const float bb = isR ? br[c] : bm[c];
      const float gg = isR ? gr[c] : gm[c];
      const float be = isR ? betar[c] : betam[c];
      const float rm = isR ? rmr[c] : rmm[c];
      const float rv = isR ? rvr[c] : rvm[c];
      const float sc = gg * rsqrtf(rv + EPSV);
      lds.colScale[tid] = sc;
      lds.colShift[tid] = (bb - rm) * sc + be;
    }
    __builtin_amdgcn_s_waitcnt(0);
    __syncthreads();
    mfma_step(lds.A, lds.Bm, waveM, waveN, quad, l15, acc);
  }
#pragma unroll
  for (int i = 0; i < 4; ++i)
#pragma unroll
    for (int p = 0; p < 4; ++p) {
      const int r = m0 + waveM * 64 + i * 16 + (quad << 2) + p;
#pragma unroll
      for (int j = 0; j < 4; ++j) {
        const int cl = waveN * 64 + j * 16 + l15;
        float v = acc[i][j][p] * lds.colScale[cl] + lds.colShift[cl];
        v = 1.f / (1.f + __expf(-v));
        const size_t idx = isR ? ((size_t)r * 2048 + n0 + cl)
                               : (OUT_M_OFF + (size_t)r * 1024 + n0 + cl);
        out[idx] = v;
      }
    }
}

// ---------------------------------------------------------------------------
extern "C" void kernel_launch(void* const* d_in, const int* in_sizes, int n_in,
                              void* d_out, int out_size, void* d_ws, size_t ws_size,
                              hipStream_t stream) {
  (void)in_sizes; (void)n_in; (void)out_size; (void)ws_size;
  const float* x      = (const float*)d_in[0];
  const float* Wm_mu  = (const float*)d_in[1];
  const float* bm_mu  = (const float*)d_in[2];
  const float* g_mu   = (const float*)d_in[3];
  const float* be_mu  = (const float*)d_in[4];
  const float* rm_mu  = (const float*)d_in[5];
  const float* rv_mu  = (const float*)d_in[6];
  const float* Wm_d   = (const float*)d_in[7];
  const float* bm_d   = (const float*)d_in[8];
  const float* g_d    = (const float*)d_in[9];
  const float* be_d   = (const float*)d_in[10];
  const float* rm_d   = (const float*)d_in[11];
  const float* rv_d   = (const float*)d_in[12];
  const float* gw1_mu = (const float*)d_in[13];
  const float* gb1_mu = (const float*)d_in[14];
  const float* gw2_mu = (const float*)d_in[15];
  const float* gb2_mu = (const float*)d_in[16];
  const float* gw1_d  = (const float*)d_in[17];
  const float* gb1_d  = (const float*)d_in[18];
  const float* gw2_d  = (const float*)d_in[19];
  const float* gb2_d  = (const float*)d_in[20];
  // d_in[21]=Wq, d_in[22]=Wk: dead (softmax over a 1x1 score == 1)
  const float* Wv     = (const float*)d_in[23];
  const float* Wp     = (const float*)d_in[24];
  const float* bp     = (const float*)d_in[25];
  const float* se_w1  = (const float*)d_in[26];
  const float* se_w2  = (const float*)d_in[27];
  const float* Wr_dec = (const float*)d_in[28];
  const float* br_dec = (const float*)d_in[29];
  const float* gr     = (const float*)d_in[30];
  const float* betar  = (const float*)d_in[31];
  const float* rmr    = (const float*)d_in[32];
  const float* rvr    = (const float*)d_in[33];
  const float* Wm_dec = (const float*)d_in[34];
  const float* bm_dec = (const float*)d_in[35];
  const float* gm     = (const float*)d_in[36];
  const float* betam  = (const float*)d_in[37];
  const float* rmm    = (const float*)d_in[38];
  const float* rvm    = (const float*)d_in[39];

  unsigned char* ws = (unsigned char*)d_ws;
  bf16* xb      = (bf16*)(ws + 0);           //  8 MiB (dead after moe_fused)
  bf16* WmT_mu  = (bf16*)(ws + 8388608);     // 16 MiB (dead after moe_fused)
  bf16* WmT_d   = (bf16*)(ws + 25165824);    // 16 MiB (dead after moe_fused)
  bf16* WvpT    = (bf16*)(ws + 41943040);    //  2 MiB
  float* gates_mu = (float*)(ws + 44040192); // 128 KiB
  float* gates_d  = (float*)(ws + 44171264); // 128 KiB
  bf16* latent  = (bf16*)(ws + 0);           //  8 MiB (overlays xb, post-moe)
  bf16* WrT     = (bf16*)(ws + 8388608);     //  4 MiB (overlays WmT_mu, post-moe)
  bf16* WmdT    = (bf16*)(ws + 12582912);    //  2 MiB

  float* out = (float*)d_out;
  float* out_mu = out + OUT_MU_OFF;
  float* out_d  = out + OUT_D_OFF;
  // Scratch in d_out regions not yet written at use time:
  bf16* Bg    = (bf16*)(out + 524288);       // r_out region (dec writes last)
  bf16* sw1T  = (bf16*)(out + 589824);
  bf16* sw2b  = (bf16*)(out + 598016);
  bf16* WpT   = (bf16*)(out + OUT_MU_OFF);            // mu region (pre-moe only)
  bf16* Wv_b  = (bf16*)(out + OUT_MU_OFF + 524288);

  const dim3 blk(256, 1, 1);

  // 1. all pre-moe transposes + converts (one dispatch)
  prep_all<<<dim3(9575, 1, 1), blk, 0, stream>>>(
      Wm_mu, Wm_d, Wp, gw1_mu, gw1_d, se_w1, x, Wv, se_w2,
      WmT_mu, WmT_d, WpT, Bg, sw1T, xb, Wv_b, sw2b);
  // 2. WvpT GEMM + gate network, concurrent in one dispatch
  gemm_gate<<<dim3(96, 1, 1), blk, 0, stream>>>(
      WpT, Wv_b, WvpT, xb, Bg, gb1_mu, gb1_d,
      gw2_mu, gb2_mu, gw2_d, gb2_d, gates_mu, gates_d);
  // 3. fused MoE (+ attn folded into mu path as 9th expert)
  moe_fused<<<dim3(32, 8, 2), blk, 0, stream>>>(
      xb, WmT_mu, WmT_d, WvpT, bm_mu, g_mu, be_mu, rm_mu, rv_mu,
      bm_d, g_d, be_d, rm_d, rv_d, bp, gates_mu, gates_d, out_mu, out_d);
  // 4. decoder weight transposes + SE, concurrent in one dispatch
  post_moe<<<dim3(1280, 1, 1), blk, 0, stream>>>(
      Wr_dec, Wm_dec, WrT, WmdT, out_mu, sw1T, sw2b, latent);
  // 5. decoders with fused BN+sigmoid epilogue
  dec_kernel<<<dim3(32, 24, 1), blk, 0, stream>>>(
      latent, WrT, WmdT, br_dec, gr, betar, rmr, rvr,
      bm_dec, gm, betam, rmm, rvm, out);
}

// Round 7
// 447.796 us; speedup vs baseline: 1.1337x; 1.0389x over previous
//
#include <hip/hip_runtime.h>
#include <hip/hip_bf16.h>

typedef __hip_bfloat16 bf16;
typedef __attribute__((ext_vector_type(4))) float f32x4;
typedef __attribute__((ext_vector_type(8))) short s16x8;
typedef __attribute__((ext_vector_type(4))) short s16x4;

#define AS1 __attribute__((address_space(1)))
#define AS3 __attribute__((address_space(3)))

#define NB      4096        // batch rows
#define EPSV    1e-5f

// d_out element offsets: (r_out, m_out, mu, d) flattened (f32 elements)
#define OUT_R_OFF   0ull
#define OUT_M_OFF   8388608ull
#define OUT_MU_OFF  12582912ull
#define OUT_D_OFF   16777216ull

__device__ __forceinline__ short f2bf(float f) {
  union { bf16 b; short s; } u;
  u.b = __float2bfloat16(f);
  return u.s;
}
__device__ __forceinline__ float bf2f(short s) {
  union { float f; unsigned u; } v;
  v.u = ((unsigned)(unsigned short)s) << 16;
  return v.f;
}

// ---------------------------------------------------------------------------
// async 16B global->LDS (wave-uniform LDS base + lane*16)
// ---------------------------------------------------------------------------
__device__ __forceinline__ void gl_lds16(const bf16* g, void* l) {
  __builtin_amdgcn_global_load_lds((const AS1 unsigned int*)g,
                                   (AS3 unsigned int*)l, 16, 0, 0);
}

// Stage a 128-row x 64-col bf16 tile from a row-major matrix with ld=1024.
// LDS layout: row-major 128 B/row, per-row rotate swizzle of the eight 16B
// k-chunks: LDS chunk c of row r holds global chunk (c + r) & 7.
__device__ __forceinline__ void stage_tile_ld1024(const bf16* __restrict__ base,
                                                  int row0, int k0,
                                                  unsigned char* ldsTile,
                                                  int wave, int lane) {
  const int srow = lane >> 3;                 // row within 8-row chunk
  const int gch  = ((lane & 7) + srow) & 7;   // swizzled global k-chunk
  const bf16* g0 = base + ((size_t)(row0 + srow) << 10) + k0 + (gch << 3);
#pragma unroll
  for (int i = 0; i < 4; ++i) {
    const int q = wave * 4 + i;               // 1KB chunk id (8 rows each)
    gl_lds16(g0 + ((size_t)(q * 8) << 10), ldsTile + (q << 10));
  }
}

// read 8 bf16 (one MFMA operand frag) for tile-row r, global k-chunk g (0..7)
__device__ __forceinline__ s16x8 read_frag(const unsigned char* ldsTile, int r, int g) {
  return *(const s16x8*)(ldsTile + r * 128 + (((g - r) & 7) << 4));
}

struct __align__(16) TileAB {
  unsigned char A[16384];    // 128 x 64 bf16
  unsigned char Bm[16384];   // 128 x 64 bf16 (B^T rows = output cols)
};

struct __align__(16) TileLds {    // TileAB + epilogue params (moe/dec kernels)
  unsigned char A[16384];
  unsigned char Bm[16384];
  float colScale[128];
  float colShift[128];
  float rowGate[128];
};

// one BK=64 step: 16 ds_read_b128 + 32 MFMA per wave
__device__ __forceinline__ void mfma_step(const unsigned char* lA, const unsigned char* lB,
                                          int waveM, int waveN, int quad, int l15,
                                          f32x4 acc[4][4]) {
#pragma unroll
  for (int kk = 0; kk < 2; ++kk) {
    const int g = (kk << 2) + quad;
    s16x8 a[4], b[4];
#pragma unroll
    for (int i = 0; i < 4; ++i) a[i] = read_frag(lA, waveM * 64 + i * 16 + l15, g);
#pragma unroll
    for (int j = 0; j < 4; ++j) b[j] = read_frag(lB, waveN * 64 + j * 16 + l15, g);
#pragma unroll
    for (int i = 0; i < 4; ++i)
#pragma unroll
      for (int j = 0; j < 4; ++j)
        acc[i][j] = __builtin_amdgcn_mfma_f32_16x16x32_bf16(a[i], b[j], acc[i][j], 0, 0, 0);
  }
}

// ---------------------------------------------------------------------------
// 64x64 transpose+convert tile helper (f32 src -> bf16 dst, dst[C][R])
// ---------------------------------------------------------------------------
__device__ __forceinline__ void tr_tile(const float* __restrict__ src,
                                        short* __restrict__ dst,
                                        int R, int C, int r0, int c0,
                                        short (*t)[68], int tid) {
  const int cc = (tid & 15) * 4;
  const int rr = tid >> 4;                    // 0..15
#pragma unroll
  for (int s = 0; s < 4; ++s) {
    const int lr = s * 16 + rr;
    const float4 v = *(const float4*)(src + (size_t)(r0 + lr) * C + c0 + cc);
    s16x4 o;
    o[0] = f2bf(v.x); o[1] = f2bf(v.y); o[2] = f2bf(v.z); o[3] = f2bf(v.w);
    *(s16x4*)(&t[lr][cc]) = o;
  }
  __syncthreads();
#pragma unroll
  for (int s = 0; s < 4; ++s) {
    const int wl = s * 16 + rr;               // local dst row (= src col)
    s16x4 o;
#pragma unroll
    for (int u = 0; u < 4; ++u) o[u] = t[cc + u][wl];
    *(s16x4*)(dst + (size_t)(c0 + wl) * R + r0 + cc) = o;
  }
}

// ---------------------------------------------------------------------------
// prep_all: ALL pre-moe transposes + converts in ONE dispatch. grid 9575.
// ---------------------------------------------------------------------------
__global__ __launch_bounds__(256) void prep_all(
    const float* __restrict__ Wm_mu, const float* __restrict__ Wm_d,
    const float* __restrict__ Wp, const float* __restrict__ gw1_mu,
    const float* __restrict__ gw1_d, const float* __restrict__ se_w1,
    const float* __restrict__ x, const float* __restrict__ Wv,
    const float* __restrict__ se_w2,
    bf16* __restrict__ WmT_mu, bf16* __restrict__ WmT_d,
    bf16* __restrict__ WpT, bf16* __restrict__ Bg, bf16* __restrict__ sw1T,
    bf16* __restrict__ xb, bf16* __restrict__ Wv_b, bf16* __restrict__ sw2b) {
  __shared__ short t[64][68];
  const int b = blockIdx.x, tid = threadIdx.x;
  if (b < 2048) {
    const int batch = b >> 8, rem = b & 255;
    const size_t ofs = (size_t)batch << 20;
    tr_tile(Wm_mu + ofs, (short*)WmT_mu + ofs, 1024, 1024,
            (rem >> 4) * 64, (rem & 15) * 64, t, tid);
  } else if (b < 4096) {
    const int bb = b - 2048;
    const int batch = bb >> 8, rem = bb & 255;
    const size_t ofs = (size_t)batch << 20;
    tr_tile(Wm_d + ofs, (short*)WmT_d + ofs, 1024, 1024,
            (rem >> 4) * 64, (rem & 15) * 64, t, tid);
  } else if (b < 4352) {
    const int bb = b - 4096;
    tr_tile(Wp, (short*)WpT, 1024, 1024, (bb >> 4) * 64, (bb & 15) * 64, t, tid);
  } else if (b < 4368) {
    tr_tile(gw1_mu, (short*)Bg, 1024, 64, (b - 4352) * 64, 0, t, tid);
  } else if (b < 4384) {
    tr_tile(gw1_d, (short*)Bg + 65536, 1024, 64, (b - 4368) * 64, 0, t, tid);
  } else if (b < 4448) {
    const int i = (b - 4384) * 256 + tid;     // 0..16383
    const int u = i >> 10, d = i & 1023;
    ((short*)sw1T)[i] = f2bf(se_w1[d * 16 + u]);
  } else {
    const int i = (b - 4448) * 256 + tid;
    const float* src; bf16* dst; int idx;
    if (i < 1048576)      { src = x;     dst = xb;   idx = i; }
    else if (i < 1310720) { src = Wv;    dst = Wv_b; idx = i - 1048576; }
    else if (i < 1311744) { src = se_w2; dst = sw2b; idx = i - 1310720; }
    else return;
    const float4 v = ((const float4*)src)[idx];
    s16x4 o;
    o[0] = f2bf(v.x); o[1] = f2bf(v.y); o[2] = f2bf(v.z); o[3] = f2bf(v.w);
    *(s16x4*)((short*)dst + (size_t)idx * 4) = o;
  }
}

// ---------------------------------------------------------------------------
// gemm_gate: one dispatch, grid 96.
// b<64:  WvpT[128x128 tile] = WpT * Wv_b^T  (m0=(b&7)*128, n0=(b>>3)*128)
// b>=64: hgates block (m0=(b-64)*128): H=relu(X@Bg^T+b1) in LDS -> softmax
// ---------------------------------------------------------------------------
__global__ __launch_bounds__(256) void gemm_gate(
    const bf16* __restrict__ WpT, const bf16* __restrict__ Wv_b,
    bf16* __restrict__ WvpT,
    const bf16* __restrict__ xb, const bf16* __restrict__ Bg,
    const float* __restrict__ gb1_mu, const float* __restrict__ gb1_d,
    const float* __restrict__ gw2_mu, const float* __restrict__ gb2_mu,
    const float* __restrict__ gw2_d, const float* __restrict__ gb2_d,
    float* __restrict__ gates_mu, float* __restrict__ gates_d) {
  __shared__ TileAB lds;
  __shared__ float H[128][132];
  __shared__ float w2l[1024];
  __shared__ float b2l[16];
  const int tid = threadIdx.x, lane = tid & 63, wave = tid >> 6;
  const int waveM = wave >> 1, waveN = wave & 1;
  const int quad = lane >> 4, l15 = lane & 15;
  if (blockIdx.x < 64) {
    const int m0 = (blockIdx.x & 7) * 128, n0 = (blockIdx.x >> 3) * 128;
    f32x4 acc[4][4] = {};
    for (int kt = 0; kt < 16; ++kt) {
      __syncthreads();
      stage_tile_ld1024(WpT, m0, kt << 6, lds.A, wave, lane);
      stage_tile_ld1024(Wv_b, n0, kt << 6, lds.Bm, wave, lane);
      __builtin_amdgcn_s_waitcnt(0);
      __syncthreads();
      mfma_step(lds.A, lds.Bm, waveM, waveN, quad, l15, acc);
    }
#pragma unroll
    for (int i = 0; i < 4; ++i)
#pragma unroll
      for (int p = 0; p < 4; ++p) {
        const int r = m0 + waveM * 64 + i * 16 + (quad << 2) + p;
#pragma unroll
        for (int j = 0; j < 4; ++j) {
          const int c = n0 + waveN * 64 + j * 16 + l15;
          ((short*)WvpT)[(size_t)r * 1024 + c] = f2bf(acc[i][j][p]);
        }
      }
  } else {
    const int m0 = (blockIdx.x - 64) * 128;
#pragma unroll
    for (int i = 0; i < 4; ++i) {
      const int idx = tid + i * 256;
      w2l[idx] = (idx < 512) ? gw2_mu[idx] : gw2_d[idx - 512];
    }
    if (tid < 16) b2l[tid] = (tid < 8) ? gb2_mu[tid] : gb2_d[tid - 8];
    f32x4 acc[4][4] = {};
    for (int kt = 0; kt < 16; ++kt) {
      __syncthreads();
      stage_tile_ld1024(xb, m0, kt << 6, lds.A, wave, lane);
      stage_tile_ld1024(Bg, 0, kt << 6, lds.Bm, wave, lane);
      __builtin_amdgcn_s_waitcnt(0);
      __syncthreads();
      mfma_step(lds.A, lds.Bm, waveM, waveN, quad, l15, acc);
    }
    float bias[4];
#pragma unroll
    for (int j = 0; j < 4; ++j) {
      const int c = waveN * 64 + j * 16 + l15;
      bias[j] = (c < 64) ? gb1_mu[c] : gb1_d[c - 64];
    }
#pragma unroll
    for (int i = 0; i < 4; ++i)
#pragma unroll
      for (int p = 0; p < 4; ++p) {
        const int r = waveM * 64 + i * 16 + (quad << 2) + p;
#pragma unroll
        for (int j = 0; j < 4; ++j) {
          const int c = waveN * 64 + j * 16 + l15;
          H[r][c] = fmaxf(acc[i][j][p] + bias[j], 0.f);
        }
      }
    __syncthreads();
    const int row = tid >> 1, path = tid & 1;
    float lg[8];
#pragma unroll
    for (int e = 0; e < 8; ++e) lg[e] = b2l[path * 8 + e];
    const float* wp = &w2l[path * 512];
    for (int j = 0; j < 64; ++j) {
      const float hv = H[row][path * 64 + j];
#pragma unroll
      for (int e = 0; e < 8; ++e) lg[e] += hv * wp[j * 8 + e];
    }
    float mx = lg[0];
#pragma unroll
    for (int e = 1; e < 8; ++e) mx = fmaxf(mx, lg[e]);
    float s = 0.f;
#pragma unroll
    for (int e = 0; e < 8; ++e) { lg[e] = __expf(lg[e] - mx); s += lg[e]; }
    const float inv = 1.f / s;
    float* gout = path ? gates_d : gates_mu;
#pragma unroll
    for (int e = 0; e < 8; ++e) gout[((size_t)(m0 + row) << 3) + e] = lg[e] * inv;
  }
}

// ---------------------------------------------------------------------------
// fused MoE+attn — EXACT round-4 structure (measured 163 us, MfmaUtil 39%):
// grid (32, 8, 2). z=0: mu = sum_e gate*relu(bn(x@W_e)) + x@Wvp + bp.
// Epilogue params staged into LDS at kt==0 (hidden under staging vmcnt wait).
// ---------------------------------------------------------------------------
__global__ __launch_bounds__(256, 2) void moe_fused(
    const bf16* __restrict__ xb, const bf16* __restrict__ WmT_mu, const bf16* __restrict__ WmT_d,
    const bf16* __restrict__ WvpT,
    const float* __restrict__ bm_mu, const float* __restrict__ g_mu, const float* __restrict__ be_mu,
    const float* __restrict__ rm_mu, const float* __restrict__ rv_mu,
    const float* __restrict__ bm_d, const float* __restrict__ g_d, const float* __restrict__ be_d,
    const float* __restrict__ rm_d, const float* __restrict__ rv_d,
    const float* __restrict__ bp,
    const float* __restrict__ gates_mu, const float* __restrict__ gates_d,
    float* __restrict__ out_mu, float* __restrict__ out_d) {
  __shared__ TileLds lds;
  const int tid = threadIdx.x, lane = tid & 63, wave = tid >> 6;
  const int waveM = wave >> 1, waveN = wave & 1;
  const int quad = lane >> 4, l15 = lane & 15;
  const int m0 = blockIdx.x * 128, n0 = blockIdx.y * 128;
  const int path = blockIdx.z;
  const int nExp = (path == 0) ? 9 : 8;
  const bf16* Wall = (path == 0) ? WmT_mu : WmT_d;
  const float* gates = (path == 0) ? gates_mu : gates_d;
  const float* bmP = (path == 0) ? bm_mu : bm_d;
  const float* gP  = (path == 0) ? g_mu : g_d;
  const float* beP = (path == 0) ? be_mu : be_d;
  const float* rmP = (path == 0) ? rm_mu : rm_d;
  const float* rvP = (path == 0) ? rv_mu : rv_d;

  f32x4 fin[4][4] = {};

  for (int e = 0; e < nExp; ++e) {
    const bool isAttn = (path == 0) && (e == 8);
    const bf16* Bmat = isAttn ? WvpT : (Wall + ((size_t)e << 20));
    f32x4 acc[4][4] = {};
    for (int kt = 0; kt < 16; ++kt) {
      __syncthreads();   // protects LDS reuse vs previous iter/expert epilogue
      stage_tile_ld1024(xb, m0, kt << 6, lds.A, wave, lane);
      stage_tile_ld1024(Bmat, n0, kt << 6, lds.Bm, wave, lane);
      if (kt == 0 && tid < 128) {           // per-expert epilogue params (f32)
        const int c = n0 + tid;
        float sc, sh, gt;
        if (isAttn) {
          sc = 1.f; sh = bp[c]; gt = 1.f;
        } else {
          const int idx = (e << 10) + c;
          sc = gP[idx] * rsqrtf(rvP[idx] + EPSV);
          sh = (bmP[idx] - rmP[idx]) * sc + beP[idx];
          gt = gates[((size_t)(m0 + tid) << 3) + e];
        }
        lds.colScale[tid] = sc;
        lds.colShift[tid] = sh;
        lds.rowGate[tid]  = gt;
      }
      __builtin_amdgcn_s_waitcnt(0);
      __syncthreads();
      mfma_step(lds.A, lds.Bm, waveM, waveN, quad, l15, acc);
    }
    // fin += gate[row] * act(acc*scale[col] + shift[col])
#pragma unroll
    for (int i = 0; i < 4; ++i) {
      const int rb = waveM * 64 + i * 16 + (quad << 2);
      float gt[4];
#pragma unroll
      for (int p = 0; p < 4; ++p) gt[p] = lds.rowGate[rb + p];
#pragma unroll
      for (int j = 0; j < 4; ++j) {
        const int c = waveN * 64 + j * 16 + l15;
        const float sc = lds.colScale[c], sh = lds.colShift[c];
#pragma unroll
        for (int p = 0; p < 4; ++p) {
          float v = acc[i][j][p] * sc + sh;
          if (!isAttn) v = fmaxf(v, 0.f);
          fin[i][j][p] += gt[p] * v;
        }
      }
    }
  }
  float* outp = (path == 0) ? out_mu : out_d;
#pragma unroll
  for (int i = 0; i < 4; ++i)
#pragma unroll
    for (int p = 0; p < 4; ++p) {
      const int r = m0 + waveM * 64 + i * 16 + (quad << 2) + p;
#pragma unroll
      for (int j = 0; j < 4; ++j) {
        const int c = n0 + waveN * 64 + j * 16 + l15;
        outp[((size_t)r << 10) + c] = fin[i][j][p];
      }
    }
}

// ---------------------------------------------------------------------------
// post_moe: one dispatch, grid 1280.
// b<512:  Wr_dec -> WrT tile   [512,768): Wm_dec -> WmdT
// b>=768: SE block (8 rows): latent = mu * sigmoid(relu(mu@se_w1)@se_w2)
// ---------------------------------------------------------------------------
__global__ __launch_bounds__(256) void post_moe(
    const float* __restrict__ Wr_dec, const float* __restrict__ Wm_dec,
    bf16* __restrict__ WrT, bf16* __restrict__ WmdT,
    const float* __restrict__ mu, const bf16* __restrict__ sw1T,
    const bf16* __restrict__ sw2b, bf16* __restrict__ latent) {
  __shared__ short t[64][68];
  __shared__ float part[16][256];
  __shared__ float part2[16][17];
  __shared__ float s1[16];
  const int b = blockIdx.x, tid = threadIdx.x;
  if (b < 512) {
    tr_tile(Wr_dec, (short*)WrT, 1024, 2048, (b >> 5) * 64, (b & 31) * 64, t, tid);
  } else if (b < 768) {
    const int bb = b - 512;
    tr_tile(Wm_dec, (short*)WmdT, 1024, 1024, (bb >> 4) * 64, (bb & 15) * 64, t, tid);
  } else {
    const int blk = b - 768;
    for (int r = 0; r < 8; ++r) {
      const int row = blk * 8 + r;
      const float4 m = *(const float4*)(mu + ((size_t)row << 10) + tid * 4);
#pragma unroll
      for (int u = 0; u < 16; ++u) {
        const s16x4 w = *(const s16x4*)((const short*)sw1T + u * 1024 + tid * 4);
        part[u][tid] = m.x * bf2f(w[0]) + m.y * bf2f(w[1])
                     + m.z * bf2f(w[2]) + m.w * bf2f(w[3]);
      }
      __syncthreads();
      {
        const int u = tid >> 4, c = tid & 15;
        float s = 0.f;
#pragma unroll
        for (int k = 0; k < 16; ++k) s += part[u][c * 16 + k];
        part2[u][c] = s;
      }
      __syncthreads();
      if (tid < 16) {
        float s = 0.f;
#pragma unroll
        for (int k = 0; k < 16; ++k) s += part2[tid][k];
        s1[tid] = fmaxf(s, 0.f);
      }
      __syncthreads();
      float o[4] = {0.f, 0.f, 0.f, 0.f};
#pragma unroll
      for (int u = 0; u < 16; ++u) {
        const s16x4 w = *(const s16x4*)((const short*)sw2b + u * 1024 + tid * 4);
        const float sv = s1[u];
        o[0] += sv * bf2f(w[0]); o[1] += sv * bf2f(w[1]);
        o[2] += sv * bf2f(w[2]); o[3] += sv * bf2f(w[3]);
      }
      const float mv[4] = {m.x, m.y, m.z, m.w};
      s16x4 ov;
#pragma unroll
      for (int tt = 0; tt < 4; ++tt)
        ov[tt] = f2bf(mv[tt] / (1.f + __expf(-o[tt])));
      *(s16x4*)((short*)latent + ((size_t)row << 10) + tid * 4) = ov;
      __syncthreads();
    }
  }
}

// ---------------------------------------------------------------------------
// decoders: r_out = sigmoid(bn(latent@Wr+br)) [N=2048], m_out [N=1024].
// grid (32, 24): nt<16 -> r path, else m path.
// ---------------------------------------------------------------------------
__global__ __launch_bounds__(256, 2) void dec_kernel(
    const bf16* __restrict__ latent, const bf16* __restrict__ WrT, const bf16* __restrict__ WmdT,
    const float* __restrict__ br, const float* __restrict__ gr, const float* __restrict__ betar,
    const float* __restrict__ rmr, const float* __restrict__ rvr,
    const float* __restrict__ bm, const float* __restrict__ gm, const float* __restrict__ betam,
    const float* __restrict__ rmm, const float* __restrict__ rvm,
    float* __restrict__ out) {
  __shared__ TileLds lds;
  const int tid = threadIdx.x, lane = tid & 63, wave = tid >> 6;
  const int waveM = wave >> 1, waveN = wave & 1;
  const int quad = lane >> 4, l15 = lane & 15;
  const int m0 = blockIdx.x * 128;
  const int nt = blockIdx.y;
  const bool isR = nt < 16;
  const int n0 = (isR ? nt : nt - 16) * 128;
  const bf16* Bt = isR ? WrT : WmdT;
  f32x4 acc[4][4] = {};
  for (int kt = 0; kt < 16; ++kt) {
    __syncthreads();
    stage_tile_ld1024(latent, m0, kt << 6, lds.A, wave, lane);
    stage_tile_ld1024(Bt, n0, kt << 6, lds.Bm, wave, lane);
    if (kt == 0 && tid < 128) {
      const int c = n0 + tid;
      const float bb = isR ? br[c] : bm[c];
      const float gg = isR ? gr[c] : gm[c];
      const float be = isR ? betar[c] : betam[c];
      const float rm = isR ? rmr[c] : rmm[c];
      const float rv = isR ? rvr[c] : rvm[c];
      const float sc = gg * rsqrtf(rv + EPSV);
      lds.colScale[tid] = sc;
      lds.colShift[tid] = (bb - rm) * sc + be;
    }
    __builtin_amdgcn_s_waitcnt(0);
    __syncthreads();
    mfma_step(lds.A, lds.Bm, waveM, waveN, quad, l15, acc);
  }
#pragma unroll
  for (int i = 0; i < 4; ++i)
#pragma unroll
    for (int p = 0; p < 4; ++p) {
      const int r = m0 + waveM * 64 + i * 16 + (quad << 2) + p;
#pragma unroll
      for (int j = 0; j < 4; ++j) {
        const int cl = waveN * 64 + j * 16 + l15;
        float v = acc[i][j][p] * lds.colScale[cl] + lds.colShift[cl];
        v = 1.f / (1.f + __expf(-v));
        const size_t idx = isR ? ((size_t)r * 2048 + n0 + cl)
                               : (OUT_M_OFF + (size_t)r * 1024 + n0 + cl);
        out[idx] = v;
      }
    }
}

// ---------------------------------------------------------------------------
extern "C" void kernel_launch(void* const* d_in, const int* in_sizes, int n_in,
                              void* d_out, int out_size, void* d_ws, size_t ws_size,
                              hipStream_t stream) {
  (void)in_sizes; (void)n_in; (void)out_size; (void)ws_size;
  const float* x      = (const float*)d_in[0];
  const float* Wm_mu  = (const float*)d_in[1];
  const float* bm_mu  = (const float*)d_in[2];
  const float* g_mu   = (const float*)d_in[3];
  const float* be_mu  = (const float*)d_in[4];
  const float* rm_mu  = (const float*)d_in[5];
  const float* rv_mu  = (const float*)d_in[6];
  const float* Wm_d   = (const float*)d_in[7];
  const float* bm_d   = (const float*)d_in[8];
  const float* g_d    = (const float*)d_in[9];
  const float* be_d   = (const float*)d_in[10];
  const float* rm_d   = (const float*)d_in[11];
  const float* rv_d   = (const float*)d_in[12];
  const float* gw1_mu = (const float*)d_in[13];
  const float* gb1_mu = (const float*)d_in[14];
  const float* gw2_mu = (const float*)d_in[15];
  const float* gb2_mu = (const float*)d_in[16];
  const float* gw1_d  = (const float*)d_in[17];
  const float* gb1_d  = (const float*)d_in[18];
  const float* gw2_d  = (const float*)d_in[19];
  const float* gb2_d  = (const float*)d_in[20];
  // d_in[21]=Wq, d_in[22]=Wk: dead (softmax over a 1x1 score == 1)
  const float* Wv     = (const float*)d_in[23];
  const float* Wp     = (const float*)d_in[24];
  const float* bp     = (const float*)d_in[25];
  const float* se_w1  = (const float*)d_in[26];
  const float* se_w2  = (const float*)d_in[27];
  const float* Wr_dec = (const float*)d_in[28];
  const float* br_dec = (const float*)d_in[29];
  const float* gr     = (const float*)d_in[30];
  const float* betar  = (const float*)d_in[31];
  const float* rmr    = (const float*)d_in[32];
  const float* rvr    = (const float*)d_in[33];
  const float* Wm_dec = (const float*)d_in[34];
  const float* bm_dec = (const float*)d_in[35];
  const float* gm     = (const float*)d_in[36];
  const float* betam  = (const float*)d_in[37];
  const float* rmm    = (const float*)d_in[38];
  const float* rvm    = (const float*)d_in[39];

  unsigned char* ws = (unsigned char*)d_ws;
  bf16* xb      = (bf16*)(ws + 0);           //  8 MiB (dead after moe_fused)
  bf16* WmT_mu  = (bf16*)(ws + 8388608);     // 16 MiB (dead after moe_fused)
  bf16* WmT_d   = (bf16*)(ws + 25165824);    // 16 MiB (dead after moe_fused)
  bf16* WvpT    = (bf16*)(ws + 41943040);    //  2 MiB
  float* gates_mu = (float*)(ws + 44040192); // 128 KiB
  float* gates_d  = (float*)(ws + 44171264); // 128 KiB
  bf16* latent  = (bf16*)(ws + 0);           //  8 MiB (overlays xb, post-moe)
  bf16* WrT     = (bf16*)(ws + 8388608);     //  4 MiB (overlays WmT_mu, post-moe)
  bf16* WmdT    = (bf16*)(ws + 12582912);    //  2 MiB

  float* out = (float*)d_out;
  float* out_mu = out + OUT_MU_OFF;
  float* out_d  = out + OUT_D_OFF;
  // Scratch in d_out regions not yet written at use time:
  bf16* Bg    = (bf16*)(out + 524288);       // r_out region (dec writes last)
  bf16* sw1T  = (bf16*)(out + 589824);
  bf16* sw2b  = (bf16*)(out + 598016);
  bf16* WpT   = (bf16*)(out + OUT_MU_OFF);            // mu region (pre-moe only)
  bf16* Wv_b  = (bf16*)(out + OUT_MU_OFF + 524288);

  const dim3 blk(256, 1, 1);

  // 1. all pre-moe transposes + converts (one dispatch)
  prep_all<<<dim3(9575, 1, 1), blk, 0, stream>>>(
      Wm_mu, Wm_d, Wp, gw1_mu, gw1_d, se_w1, x, Wv, se_w2,
      WmT_mu, WmT_d, WpT, Bg, sw1T, xb, Wv_b, sw2b);
  // 2. WvpT GEMM + gate network, concurrent in one dispatch
  gemm_gate<<<dim3(96, 1, 1), blk, 0, stream>>>(
      WpT, Wv_b, WvpT, xb, Bg, gb1_mu, gb1_d,
      gw2_mu, gb2_mu, gw2_d, gb2_d, gates_mu, gates_d);
  // 3. fused MoE (round-4 structure; + attn folded into mu path as 9th expert)
  moe_fused<<<dim3(32, 8, 2), blk, 0, stream>>>(
      xb, WmT_mu, WmT_d, WvpT, bm_mu, g_mu, be_mu, rm_mu, rv_mu,
      bm_d, g_d, be_d, rm_d, rv_d, bp, gates_mu, gates_d, out_mu, out_d);
  // 4. decoder weight transposes + SE, concurrent in one dispatch
  post_moe<<<dim3(1280, 1, 1), blk, 0, stream>>>(
      Wr_dec, Wm_dec, WrT, WmdT, out_mu, sw1T, sw2b, latent);
  // 5. decoders with fused BN+sigmoid epilogue
  dec_kernel<<<dim3(32, 24, 1), blk, 0, stream>>>(
      latent, WrT, WmdT, br_dec, gr, betar, rmr, rvr,
      bm_dec, gm, betam, rmm, rvm, out);
}